// Round 1
// baseline (414.095 us; speedup 1.0000x reference)
//
#include <hip/hip_runtime.h>
#include <math.h>
#include <stdint.h>

#define NV 8192        // N (nodes)
#define KD 256         // IN_DIM
#define DD 64          // OUT_DIM
#define ALPHA 0.2f
#define TI 64          // rows per block tile
#define CJ 128         // j-chunk (16 chunks of 8 f16)
#define BLK 512

typedef _Float16 half8 __attribute__((ext_vector_type(8)));
typedef float floatx4 __attribute__((ext_vector_type(4)));

// ws layout (float offsets)
#define OFF_WHT  0                        // WhT f16 [DD][NV] = 262144 floats
#define OFF_F1   (DD * NV / 2)
#define OFF_F2   (OFF_F1 + NV)
#define OFF_PACC (OFF_F2 + NV)            // then pacc[S][NV][DD], pl[S][NV]

// ---------------- kernel 1: WhT(f16) = (h@W)^T, f1 = Wh@a1, f2 = Wh@a2 ----------------
__global__ __launch_bounds__(256) void gat_pre(
    const float* __restrict__ h, const float* __restrict__ W,
    const float* __restrict__ a, ushort* __restrict__ whT,
    float* __restrict__ f1, float* __restrict__ f2) {
  __shared__ float hrow[4][KD];
  __shared__ __align__(8) ushort tw[DD][4];  // transpose buffer [d][i']
  const int wv = threadIdx.x >> 6, lane = threadIdx.x & 63;
  const int i = blockIdx.x * 4 + wv;
  *(float4*)&hrow[wv][lane * 4] = *(const float4*)&h[(long long)i * KD + lane * 4];
  __syncthreads();
  float wh = 0.f;
#pragma unroll 8
  for (int c = 0; c < KD; ++c) wh += hrow[wv][c] * W[c * DD + lane];
  float p1 = wh * a[lane];
  float p2 = wh * a[DD + lane];
#pragma unroll
  for (int off = 32; off > 0; off >>= 1) {
    p1 += __shfl_down(p1, off);
    p2 += __shfl_down(p2, off);
  }
  if (lane == 0) { f1[i] = p1; f2[i] = p2; }
  union { _Float16 hf; ushort u; } cv;
  cv.hf = (_Float16)wh;
  tw[lane][wv] = cv.u;
  __syncthreads();
  if (threadIdx.x < DD) {  // write 4 i-values of row d: 8 B store
    *(uint2*)&whT[(long long)threadIdx.x * NV + blockIdx.x * 4] = *(uint2*)&tw[threadIdx.x][0];
  }
}

// ---------------- kernel 2: fused masked-softmax attention @ Wh (MFMA f16) ----------------
// R3: 2-phase reg-staged pipeline (T3/T4 minimum recipe + T14):
//  - prefetch chunk ch+1 (A int4 x4, whT uint4 x2, f2 float4) into regs BEFORE the
//    pre-MFMA barrier; raw s_barrier + lgkmcnt(0) only (NO vmcnt drain -> loads stay
//    in flight across barrier+MFMA+barrier; consumed next iter via compiler-auto vmcnt).
//    whT loads issued before A loads, so A-consumption's vmcnt(0) implies whT landed.
//  - sched_barrier(0) fences around each raw barrier (rule #18 hoisting hazard).
//  - S=8 j-splits (grid 1024) for finer block granularity; A/whT/exp totals S-invariant.
// LDS layouts and XOR swizzles unchanged from the verified R2 kernel (numerics identical
// per chunk; only chunk count per s changes).
__global__ __launch_bounds__(BLK) void gat_main(
    const int* __restrict__ A, const ushort* __restrict__ whT,
    const float* __restrict__ f1, const float* __restrict__ f2,
    float* __restrict__ pacc, float* __restrict__ pl, int S) {
  __shared__ __align__(16) ushort w_lds[TI * CJ];  // 16 KB, A-operand (rows i)
  __shared__ __align__(16) ushort b_lds[TI * CJ];  // 16 KB, B-operand (rows d)
  __shared__ float f1_lds[TI], M_lds[TI], redf[8];

  const int tid = threadIdx.x;
  const int wave = tid >> 6, lane = tid & 63;
  const int tile = blockIdx.x & 127;  // NV/TI = 128
  const int s = blockIdx.x >> 7;
  const int i0 = tile * TI;
  const int jrange = NV / S;
  const int j0 = s * jrange;

  // block-redundant global max of f2
  float m = -1e30f;
#pragma unroll
  for (int q = 0; q < 16; ++q) m = fmaxf(m, f2[tid + q * BLK]);
#pragma unroll
  for (int off = 32; off > 0; off >>= 1) m = fmaxf(m, __shfl_down(m, off));
  if (lane == 0) redf[wave] = m;
  __syncthreads();
  if (tid < TI) {
    float mm = redf[0];
#pragma unroll
    for (int k = 1; k < 8; ++k) mm = fmaxf(mm, redf[k]);
    float v = f1[i0 + tid];
    f1_lds[tid] = v;
    float x = v + mm;                      // M_i = lrelu(f1_i + max f2) >= all row
    M_lds[tid] = x > 0.f ? x : ALPHA * x;  // logits (lrelu monotone) -> w <= 1, f16-safe
  }
  __syncthreads();  // M_lds/f1_lds visible (prologue; full drain here is fine, once)

  // stage-1 mapping: thread covers cols c4..c4+3 of rows rb+16p
  const int c4 = (tid & 31) * 4;
  const int k8w = (tid & 31) >> 1;   // 16B-chunk col for writes
  const int sub = (tid & 1) * 8;     // byte offset within chunk
  const int rb = tid >> 5;           // 0..15
  // MFMA mapping: wave -> m-tile (wave>>1), two n-tiles
  const int mt = wave >> 1;
  const int nt0 = (wave & 1) * 2;
  const int m_ = lane & 15, quad = lane >> 4;

  // hoist per-row f1/M (fixed rows per thread across all chunks)
  float f1r[4], Mr[4];
#pragma unroll
  for (int p = 0; p < 4; ++p) {
    f1r[p] = f1_lds[rb + 16 * p];
    Mr[p] = M_lds[rb + 16 * p];
  }

  floatx4 acc0 = {0.f, 0.f, 0.f, 0.f}, acc1 = {0.f, 0.f, 0.f, 0.f};
  float lp[4] = {0.f, 0.f, 0.f, 0.f};

  const int nch = jrange / CJ;

  // ---- prologue prefetch: chunk 0 into regs (whT first, then f2, then A) ----
  uint4 bw[2];
  int4 Ar[4];
  float4 f2v;
  {
    const int jb = j0;
#pragma unroll
    for (int u = 0; u < 2; ++u) {
      const int idx = tid + u * BLK;
      const int n = idx >> 4, c = idx & 15;
      bw[u] = *(const uint4*)(whT + (long long)n * NV + jb + 8 * (c ^ (n & 15)));
    }
    f2v = *(const float4*)(f2 + jb + c4);
#pragma unroll
    for (int p = 0; p < 4; ++p)
      Ar[p] = *(const int4*)(A + (long long)(i0 + rb + 16 * p) * NV + jb + c4);
  }

  for (int ch = 0; ch < nch; ++ch) {
    // ---- stage B chunk from prefetched regs (auto vmcnt wait on bw here) ----
#pragma unroll
    for (int u = 0; u < 2; ++u) *(uint4*)&b_lds[(tid + u * BLK) * 8] = bw[u];

    // ---- stage 1: w = A ? exp(lrelu(f1+f2) - M) : 0, as f16 into w_lds ----
#pragma unroll
    for (int p = 0; p < 4; ++p) {
      const int r = rb + 16 * p;
      const int4 a4 = Ar[p];
      const float f1p = f1r[p], Mp = Mr[p];
      float w0, w1, w2, w3;
      { float x = f1p + f2v.x; x = x > 0.f ? x : ALPHA * x; w0 = (a4.x > 0) ? __expf(x - Mp) : 0.f; }
      { float x = f1p + f2v.y; x = x > 0.f ? x : ALPHA * x; w1 = (a4.y > 0) ? __expf(x - Mp) : 0.f; }
      { float x = f1p + f2v.z; x = x > 0.f ? x : ALPHA * x; w2 = (a4.z > 0) ? __expf(x - Mp) : 0.f; }
      { float x = f1p + f2v.w; x = x > 0.f ? x : ALPHA * x; w3 = (a4.w > 0) ? __expf(x - Mp) : 0.f; }
      union { _Float16 hf[4]; uint2 u2; } pk;
      pk.hf[0] = (_Float16)w0; pk.hf[1] = (_Float16)w1;
      pk.hf[2] = (_Float16)w2; pk.hf[3] = (_Float16)w3;
      // sum the f16-rounded values so softmax stays exactly normalized
      lp[p] += (float)pk.hf[0] + (float)pk.hf[1] + (float)pk.hf[2] + (float)pk.hf[3];
      *(uint2*)((char*)w_lds + (r * 16 + (k8w ^ (r & 15))) * 16 + sub) = pk.u2;
    }

    // ---- prefetch chunk ch+1: issued BEFORE barrier, in flight across MFMA ----
    if (ch + 1 < nch) {
      const int jb = j0 + (ch + 1) * CJ;
#pragma unroll
      for (int u = 0; u < 2; ++u) {
        const int idx = tid + u * BLK;
        const int n = idx >> 4, c = idx & 15;
        bw[u] = *(const uint4*)(whT + (long long)n * NV + jb + 8 * (c ^ (n & 15)));
      }
      f2v = *(const float4*)(f2 + jb + c4);
#pragma unroll
      for (int p = 0; p < 4; ++p)
        Ar[p] = *(const int4*)(A + (long long)(i0 + rb + 16 * p) * NV + jb + c4);
    }

    // ---- barrier 1 (no vmcnt drain): my LDS writes visible to all waves ----
    asm volatile("s_waitcnt lgkmcnt(0)" ::: "memory");
    __builtin_amdgcn_sched_barrier(0);
    __builtin_amdgcn_s_barrier();
    __builtin_amdgcn_sched_barrier(0);

    // ---- stage 2: MFMA, 2 C-tiles per wave, 4 k-steps ----
    __builtin_amdgcn_s_setprio(1);
#pragma unroll
    for (int ks = 0; ks < 4; ++ks) {
      const int cc = 4 * ks + quad;
      const half8 af = *(const half8*)((const char*)w_lds + (((16 * mt + m_) * 16) + (cc ^ m_)) * 16);
      const half8 b0 = *(const half8*)((const char*)b_lds + (((16 * nt0 + m_) * 16) + (cc ^ m_)) * 16);
      const half8 b1 = *(const half8*)((const char*)b_lds + (((16 * (nt0 + 1) + m_) * 16) + (cc ^ m_)) * 16);
      acc0 = __builtin_amdgcn_mfma_f32_16x16x32_f16(af, b0, acc0, 0, 0, 0);
      acc1 = __builtin_amdgcn_mfma_f32_16x16x32_f16(af, b1, acc1, 0, 0, 0);
    }
    __builtin_amdgcn_s_setprio(0);

    // ---- barrier 2 (no vmcnt drain): all readers done before next overwrite ----
    asm volatile("s_waitcnt lgkmcnt(0)" ::: "memory");
    __builtin_amdgcn_sched_barrier(0);
    __builtin_amdgcn_s_barrier();
    __builtin_amdgcn_sched_barrier(0);
  }

  // ---- pl: reduce thread-local row-sum partials across each 32-lane group ----
#pragma unroll
  for (int p = 0; p < 4; ++p) {
    float v = lp[p];
    v += __shfl_down(v, 16, 32);
    v += __shfl_down(v, 8, 32);
    v += __shfl_down(v, 4, 32);
    v += __shfl_down(v, 2, 32);
    v += __shfl_down(v, 1, 32);
    if ((tid & 31) == 0) pl[(long long)s * NV + i0 + rb + 16 * p] = v;
  }

  // ---- epilogue: C/D layout row=quad*4+reg, col=lane&15 (verified m89/m91) ----
#pragma unroll
  for (int reg = 0; reg < 4; ++reg) {
    const int i = i0 + 16 * mt + quad * 4 + reg;
    const long long base = ((long long)s * NV + i) * DD + m_;
    pacc[base + 16 * nt0] = acc0[reg];
    pacc[base + 16 * (nt0 + 1)] = acc1[reg];
  }
}

// ---------------- kernel 3: combine j-splits, normalize, ELU ----------------
__global__ __launch_bounds__(256) void gat_fin(const float* __restrict__ pacc,
                                               const float* __restrict__ pl,
                                               float* __restrict__ out, int S) {
  const int idx = blockIdx.x * 256 + threadIdx.x;
  const int i = idx >> 6;
  float sum = 0.f, l = 0.f;
  for (int q = 0; q < S; ++q) sum += pacc[(long long)q * (NV * DD) + idx];
  for (int q = 0; q < S; ++q) l += pl[q * NV + i];
  const float v = sum / l;
  out[idx] = v > 0.f ? v : expm1f(v);  // ELU, alpha=1
}

extern "C" void kernel_launch(void* const* d_in, const int* in_sizes, int n_in,
                              void* d_out, int out_size, void* d_ws, size_t ws_size,
                              hipStream_t stream) {
  const float* h = (const float*)d_in[0];
  const int* A = (const int*)d_in[1];
  const float* W = (const float*)d_in[2];
  const float* a = (const float*)d_in[3];
  float* out = (float*)d_out;
  float* ws = (float*)d_ws;

  ushort* whT = (ushort*)(ws + OFF_WHT);
  float* f1 = ws + OFF_F1;
  float* f2 = ws + OFF_F2;
  float* pacc = ws + OFF_PACC;

  // pick largest j-split S that fits the workspace (R3: default 8 for occupancy)
  int S = 8;
  while (S > 1 &&
         (size_t)(OFF_PACC + (size_t)S * (NV * DD + NV)) * sizeof(float) > ws_size)
    S >>= 1;
  float* pl = pacc + (size_t)S * NV * DD;

  gat_pre<<<NV / 4, 256, 0, stream>>>(h, W, a, whT, f1, f2);
  gat_main<<<(NV / TI) * S, BLK, 0, stream>>>(A, whT, f1, f2, pacc, pl, S);
  gat_fin<<<NV * DD / 256, 256, 0, stream>>>(pacc, pl, out, S);
}

// Round 2
// 397.647 us; speedup vs baseline: 1.0414x; 1.0414x over previous
//
#include <hip/hip_runtime.h>
#include <math.h>
#include <stdint.h>

#define NV 8192        // N (nodes)
#define KD 256         // IN_DIM
#define DD 64          // OUT_DIM
#define ALPHA 0.2f
#define TI 64          // rows per block tile
#define CJ 128         // j-chunk (16 chunks of 8 f16)
#define BLK 512

typedef _Float16 half8 __attribute__((ext_vector_type(8)));
typedef float floatx4 __attribute__((ext_vector_type(4)));

// ws layout (float offsets)
#define OFF_WHT  0                        // WhT f16 [DD][NV] = 262144 floats
#define OFF_F1   (DD * NV / 2)
#define OFF_F2   (OFF_F1 + NV)
#define OFF_PACC (OFF_F2 + NV)            // then pacc[S][NV][DD], pl[S][NV]

// ---------------- kernel 1: WhT(f16) = (h@W)^T, f1 = Wh@a1, f2 = Wh@a2 ----------------
__global__ __launch_bounds__(256) void gat_pre(
    const float* __restrict__ h, const float* __restrict__ W,
    const float* __restrict__ a, ushort* __restrict__ whT,
    float* __restrict__ f1, float* __restrict__ f2) {
  __shared__ float hrow[4][KD];
  __shared__ __align__(8) ushort tw[DD][4];  // transpose buffer [d][i']
  const int wv = threadIdx.x >> 6, lane = threadIdx.x & 63;
  const int i = blockIdx.x * 4 + wv;
  *(float4*)&hrow[wv][lane * 4] = *(const float4*)&h[(long long)i * KD + lane * 4];
  __syncthreads();
  float wh = 0.f;
#pragma unroll 8
  for (int c = 0; c < KD; ++c) wh += hrow[wv][c] * W[c * DD + lane];
  float p1 = wh * a[lane];
  float p2 = wh * a[DD + lane];
#pragma unroll
  for (int off = 32; off > 0; off >>= 1) {
    p1 += __shfl_down(p1, off);
    p2 += __shfl_down(p2, off);
  }
  if (lane == 0) { f1[i] = p1; f2[i] = p2; }
  union { _Float16 hf; ushort u; } cv;
  cv.hf = (_Float16)wh;
  tw[lane][wv] = cv.u;
  __syncthreads();
  if (threadIdx.x < DD) {  // write 4 i-values of row d: 8 B store
    *(uint2*)&whT[(long long)threadIdx.x * NV + blockIdx.x * 4] = *(uint2*)&tw[threadIdx.x][0];
  }
}

// ---------------- kernel 2: fused masked-softmax attention @ Wh (MFMA f16) ----------------
// R4 (= R0 structure + minimal pipeline):
//  - S back to 4 (R1's S=8 regressed: blocks/CU capped ~2 by LDS/VGPR, extra blocks
//    just added prologue/pacc overhead). j-partition bitwise-identical to R0.
//  - A-ONLY register prefetch, 1 chunk deep (16 VGPR): A is the sole HBM stream
//    (256 MB read-once, ~900cyc latency); whT(1MB)/f2(32KB) are L2-resident and
//    loaded fresh at loop top with stage-1 VALU (~500cyc) as latency cover.
//    Ar[p] refilled immediately after consumption inside the p-loop (no dbuf).
//  - raw s_barrier + lgkmcnt(0) only (no vmcnt drain) so prefetched A stays in
//    flight across barrier+MFMA+barrier; consumption next chunk gets compiler-auto
//    vmcnt waits. Correctness of this barrier structure validated by R1's pass.
//  - sched_barrier(0) fences around raw barriers (rule #18 hoisting hazard).
// LDS layouts and XOR swizzles unchanged from R0.
__global__ __launch_bounds__(BLK) void gat_main(
    const int* __restrict__ A, const ushort* __restrict__ whT,
    const float* __restrict__ f1, const float* __restrict__ f2,
    float* __restrict__ pacc, float* __restrict__ pl, int S) {
  __shared__ __align__(16) ushort w_lds[TI * CJ];  // 16 KB, A-operand (rows i)
  __shared__ __align__(16) ushort b_lds[TI * CJ];  // 16 KB, B-operand (rows d)
  __shared__ float f1_lds[TI], M_lds[TI], redf[8];

  const int tid = threadIdx.x;
  const int wave = tid >> 6, lane = tid & 63;
  const int tile = blockIdx.x & 127;  // NV/TI = 128
  const int s = blockIdx.x >> 7;
  const int i0 = tile * TI;
  const int jrange = NV / S;
  const int j0 = s * jrange;

  // block-redundant global max of f2
  float m = -1e30f;
#pragma unroll
  for (int q = 0; q < 16; ++q) m = fmaxf(m, f2[tid + q * BLK]);
#pragma unroll
  for (int off = 32; off > 0; off >>= 1) m = fmaxf(m, __shfl_down(m, off));
  if (lane == 0) redf[wave] = m;
  __syncthreads();
  if (tid < TI) {
    float mm = redf[0];
#pragma unroll
    for (int k = 1; k < 8; ++k) mm = fmaxf(mm, redf[k]);
    float v = f1[i0 + tid];
    f1_lds[tid] = v;
    float x = v + mm;                      // M_i = lrelu(f1_i + max f2) >= all row
    M_lds[tid] = x > 0.f ? x : ALPHA * x;  // logits (lrelu monotone) -> w <= 1, f16-safe
  }
  __syncthreads();  // M_lds/f1_lds visible before hoisted reads (full drain once, fine)

  // stage-1 mapping: thread covers cols c4..c4+3 of rows rb+16p
  const int c4 = (tid & 31) * 4;
  const int k8w = (tid & 31) >> 1;   // 16B-chunk col for writes
  const int sub = (tid & 1) * 8;     // byte offset within chunk
  const int rb = tid >> 5;           // 0..15
  // MFMA mapping: wave -> m-tile (wave>>1), two n-tiles
  const int mt = wave >> 1;
  const int nt0 = (wave & 1) * 2;
  const int m_ = lane & 15, quad = lane >> 4;

  // hoist per-row f1/M (fixed rows per thread across all chunks)
  float f1r[4], Mr[4];
#pragma unroll
  for (int p = 0; p < 4; ++p) {
    f1r[p] = f1_lds[rb + 16 * p];
    Mr[p] = M_lds[rb + 16 * p];
  }

  floatx4 acc0 = {0.f, 0.f, 0.f, 0.f}, acc1 = {0.f, 0.f, 0.f, 0.f};
  float lp[4] = {0.f, 0.f, 0.f, 0.f};

  const int nch = jrange / CJ;

  // ---- prologue: prefetch chunk 0's A-tile into regs ----
  int4 Ar[4];
#pragma unroll
  for (int p = 0; p < 4; ++p)
    Ar[p] = *(const int4*)(A + (long long)(i0 + rb + 16 * p) * NV + j0 + c4);

  for (int ch = 0; ch < nch; ++ch) {
    const int jb = j0 + ch * CJ;

    // ---- issue whT/f2 loads for THIS chunk (L2-resident; covered by stage-1) ----
    uint4 bw[2];
#pragma unroll
    for (int u = 0; u < 2; ++u) {
      const int idx = tid + u * BLK;  // 0..1023 chunk slots
      const int n = idx >> 4, c = idx & 15;
      bw[u] = *(const uint4*)(whT + (long long)n * NV + jb + 8 * (c ^ (n & 15)));
    }
    const float4 f2v = *(const float4*)(f2 + jb + c4);

    // ---- stage 1: w = A ? exp(lrelu(f1+f2) - M) : 0, as f16 into w_lds ----
    // consume Ar[p], then immediately refill it for chunk ch+1 (HBM load stays
    // in flight across barrier + MFMA + barrier; no vmcnt drain below).
#pragma unroll
    for (int p = 0; p < 4; ++p) {
      const int r = rb + 16 * p;
      const int4 a4 = Ar[p];
      if (ch + 1 < nch)
        Ar[p] = *(const int4*)(A + (long long)(i0 + r) * NV + jb + CJ + c4);
      const float f1p = f1r[p], Mp = Mr[p];
      float w0, w1, w2, w3;
      { float x = f1p + f2v.x; x = x > 0.f ? x : ALPHA * x; w0 = (a4.x > 0) ? __expf(x - Mp) : 0.f; }
      { float x = f1p + f2v.y; x = x > 0.f ? x : ALPHA * x; w1 = (a4.y > 0) ? __expf(x - Mp) : 0.f; }
      { float x = f1p + f2v.z; x = x > 0.f ? x : ALPHA * x; w2 = (a4.z > 0) ? __expf(x - Mp) : 0.f; }
      { float x = f1p + f2v.w; x = x > 0.f ? x : ALPHA * x; w3 = (a4.w > 0) ? __expf(x - Mp) : 0.f; }
      union { _Float16 hf[4]; uint2 u2; } pk;
      pk.hf[0] = (_Float16)w0; pk.hf[1] = (_Float16)w1;
      pk.hf[2] = (_Float16)w2; pk.hf[3] = (_Float16)w3;
      // sum the f16-rounded values so softmax stays exactly normalized
      lp[p] += (float)pk.hf[0] + (float)pk.hf[1] + (float)pk.hf[2] + (float)pk.hf[3];
      *(uint2*)((char*)w_lds + (r * 16 + (k8w ^ (r & 15))) * 16 + sub) = pk.u2;
    }

    // ---- stage B chunk: write b_lds from bw (auto vmcnt wait on bw only) ----
#pragma unroll
    for (int u = 0; u < 2; ++u) *(uint4*)&b_lds[(tid + u * BLK) * 8] = bw[u];

    // ---- barrier 1 (lgkm only, no vmcnt drain): LDS writes visible ----
    asm volatile("s_waitcnt lgkmcnt(0)" ::: "memory");
    __builtin_amdgcn_sched_barrier(0);
    __builtin_amdgcn_s_barrier();
    __builtin_amdgcn_sched_barrier(0);

    // ---- stage 2: MFMA, 2 C-tiles per wave, 4 k-steps ----
    __builtin_amdgcn_s_setprio(1);
#pragma unroll
    for (int ks = 0; ks < 4; ++ks) {
      const int cc = 4 * ks + quad;
      const half8 af = *(const half8*)((const char*)w_lds + (((16 * mt + m_) * 16) + (cc ^ m_)) * 16);
      const half8 b0 = *(const half8*)((const char*)b_lds + (((16 * nt0 + m_) * 16) + (cc ^ m_)) * 16);
      const half8 b1 = *(const half8*)((const char*)b_lds + (((16 * (nt0 + 1) + m_) * 16) + (cc ^ m_)) * 16);
      acc0 = __builtin_amdgcn_mfma_f32_16x16x32_f16(af, b0, acc0, 0, 0, 0);
      acc1 = __builtin_amdgcn_mfma_f32_16x16x32_f16(af, b1, acc1, 0, 0, 0);
    }
    __builtin_amdgcn_s_setprio(0);

    // ---- barrier 2 (lgkm only): all readers done before next chunk's writes ----
    asm volatile("s_waitcnt lgkmcnt(0)" ::: "memory");
    __builtin_amdgcn_sched_barrier(0);
    __builtin_amdgcn_s_barrier();
    __builtin_amdgcn_sched_barrier(0);
  }

  // ---- pl: reduce thread-local row-sum partials across each 32-lane group ----
#pragma unroll
  for (int p = 0; p < 4; ++p) {
    float v = lp[p];
    v += __shfl_down(v, 16, 32);
    v += __shfl_down(v, 8, 32);
    v += __shfl_down(v, 4, 32);
    v += __shfl_down(v, 2, 32);
    v += __shfl_down(v, 1, 32);
    if ((tid & 31) == 0) pl[(long long)s * NV + i0 + rb + 16 * p] = v;
  }

  // ---- epilogue: C/D layout row=quad*4+reg, col=lane&15 (verified m89/m91) ----
#pragma unroll
  for (int reg = 0; reg < 4; ++reg) {
    const int i = i0 + 16 * mt + quad * 4 + reg;
    const long long base = ((long long)s * NV + i) * DD + m_;
    pacc[base + 16 * nt0] = acc0[reg];
    pacc[base + 16 * (nt0 + 1)] = acc1[reg];
  }
}

// ---------------- kernel 3: combine j-splits, normalize, ELU ----------------
__global__ __launch_bounds__(256) void gat_fin(const float* __restrict__ pacc,
                                               const float* __restrict__ pl,
                                               float* __restrict__ out, int S) {
  const int idx = blockIdx.x * 256 + threadIdx.x;
  const int i = idx >> 6;
  float sum = 0.f, l = 0.f;
  for (int q = 0; q < S; ++q) sum += pacc[(long long)q * (NV * DD) + idx];
  for (int q = 0; q < S; ++q) l += pl[q * NV + i];
  const float v = sum / l;
  out[idx] = v > 0.f ? v : expm1f(v);  // ELU, alpha=1
}

extern "C" void kernel_launch(void* const* d_in, const int* in_sizes, int n_in,
                              void* d_out, int out_size, void* d_ws, size_t ws_size,
                              hipStream_t stream) {
  const float* h = (const float*)d_in[0];
  const int* A = (const int*)d_in[1];
  const float* W = (const float*)d_in[2];
  const float* a = (const float*)d_in[3];
  float* out = (float*)d_out;
  float* ws = (float*)d_ws;

  ushort* whT = (ushort*)(ws + OFF_WHT);
  float* f1 = ws + OFF_F1;
  float* f2 = ws + OFF_F2;
  float* pacc = ws + OFF_PACC;

  // pick largest j-split S that fits the workspace (S=4: 512 blocks saturates
  // 256 CUs at ~2 blocks/CU; S=8 measured worse in R1)
  int S = 4;
  while (S > 1 &&
         (size_t)(OFF_PACC + (size_t)S * (NV * DD + NV)) * sizeof(float) > ws_size)
    S >>= 1;
  float* pl = pacc + (size_t)S * NV * DD;

  gat_pre<<<NV / 4, 256, 0, stream>>>(h, W, a, whT, f1, f2);
  gat_main<<<(NV / TI) * S, BLK, 0, stream>>>(A, whT, f1, f2, pacc, pl, S);
  gat_fin<<<NV * DD / 256, 256, 0, stream>>>(pacc, pl, out, S);
}